// Round 16
// baseline (339.384 us; speedup 1.0000x reference)
//
#include <hip/hip_runtime.h>
#include <stdint.h>

#define D_MODEL 2048
#define RANK    64
#define BATCH   16384

#define BM      32      // batch rows per block
#define CHUNK   256     // K staged per barrier-pair (8 chunks total)
#define LDAC    264     // padded u16 row stride for x chunk (528 B)
#define LDAN    72      // padded u16 row stride for nre LDS

typedef unsigned short u16;
typedef __attribute__((ext_vector_type(8))) short  bf16x8;
typedef __attribute__((ext_vector_type(4))) float  f32x4;
typedef __attribute__((ext_vector_type(4))) unsigned short u16x4;
typedef __attribute__((ext_vector_type(8))) unsigned short u16x8;

// ws layout (u16 elements) — MFMA-fragment-packed weights:
// P1: [ntile 12][kwin 64][lane 64][8]  A-frags of {W_dt;W_ph;W_B}
// P2: [dtile 128][kwin 2][lane 64][8]  A-frags of W_C
#define P1_HI 0
#define P1_LO 393216
#define P2_HI 786432
#define P2_LO 917504
// total 2 MiB

__device__ __forceinline__ u16 f2bf(float f) {
    uint32_t u = __float_as_uint(f);
    u += 0x7fffu + ((u >> 16) & 1u);      // RNE
    return (u16)(u >> 16);
}
__device__ __forceinline__ float bf2f(u16 h) {
    return __uint_as_float(((uint32_t)h) << 16);
}

#define MFMA(a, b, c) __builtin_amdgcn_mfma_f32_16x16x32_bf16((a), (b), (c), 0, 0, 0)

// ---------------- prep: split + pack weights into fragment order (unchanged) ----------------
__global__ __launch_bounds__(256) void prep_pack(
    const float* __restrict__ Wdt, const float* __restrict__ Wph,
    const float* __restrict__ WB,  const float* __restrict__ WC,
    u16* __restrict__ ws)
{
    const int t = blockIdx.x * 256 + threadIdx.x;
    const float* src;
    u16 *dhi, *dlo;
    if (t < 49152) {                          // P1: 12*64*64 frag slots
        const int lane = t & 63;
        const int row  = (t >> 12) * 16 + (lane & 15);
        const int k0   = ((t >> 6) & 63) * 32 + (lane >> 4) * 8;
        src = (row < 64)  ? Wdt + row * 2048 + k0
            : (row < 128) ? Wph + (row - 64) * 2048 + k0
                          : WB  + (row - 128) * 2048 + k0;
        dhi = ws + P1_HI + t * 8;
        dlo = ws + P1_LO + t * 8;
    } else {                                  // P2: 128*2*64 frag slots
        const int t2   = t - 49152;
        const int lane = t2 & 63;
        const int row  = (t2 >> 7) * 16 + (lane & 15);
        const int k0   = ((t2 >> 6) & 1) * 32 + (lane >> 4) * 8;
        src = WC + row * 64 + k0;
        dhi = ws + P2_HI + t2 * 8;
        dlo = ws + P2_LO + t2 * 8;
    }
    const f32x4 a = *(const f32x4*)src;
    const f32x4 b = *(const f32x4*)(src + 4);
    u16x8 hi, lo;
    #pragma unroll
    for (int j = 0; j < 4; ++j) {
        hi[j]     = f2bf(a[j]);
        lo[j]     = f2bf(a[j] - bf2f(hi[j]));
        hi[4 + j] = f2bf(b[j]);
        lo[4 + j] = f2bf(b[j] - bf2f(hi[4 + j]));
    }
    *(u16x8*)dhi = hi;
    *(u16x8*)dlo = lo;
}

// ---------------- fused main kernel v4 ----------------
// Same structure as R12 (256-K chunks, 8 barrier-pairs, 512 thr = 8 waves).
// NEW: kwin loop fully unrolled with 2-deep double-buffered weight-frag
// pipeline -> kwin k+2's 6 global loads are in flight during kwin k's MFMAs,
// hiding the ~250cy L2 latency that R12 exposed per kwin (VGPR was 52!).
// T5 setprio around MFMA clusters (2 desynced blocks/CU = role diversity).
__global__ __launch_bounds__(512, 4) void mamba_v4(
    const float* __restrict__ x,
    const float* __restrict__ state_re, const float* __restrict__ state_im,
    const float* __restrict__ b_dt, const float* __restrict__ b_ph,
    const float* __restrict__ A_real, const float* __restrict__ A_imag,
    const u16* __restrict__ ws,
    float* __restrict__ dout)
{
    __shared__ __align__(16) u16 xa_hi[BM * LDAC];
    __shared__ __align__(16) u16 xa_lo[BM * LDAC];
    __shared__ __align__(16) u16 nr_hi[BM * LDAN];
    __shared__ __align__(16) u16 nr_lo[BM * LDAN];

    const u16* p1_hi = ws + P1_HI;
    const u16* p1_lo = ws + P1_LO;
    const u16* p2_hi = ws + P2_HI;
    const u16* p2_lo = ws + P2_LO;

    const int tid  = threadIdx.x;
    const int w    = tid >> 6;
    const int wm   = w >> 2;            // batch half 0..1
    const int wg   = w & 3;             // n-tile / d-col split 0..3
    const int lane = tid & 63;
    const int l15  = tid & 15;
    const int lg   = lane >> 4;         // k-group 0..3
    const int r0   = blockIdx.x * BM;

    const int srow = tid >> 4;          // staging: x[r0+srow][c*256 + skc .. +16)
    const int skc  = (tid & 15) << 4;
    const float* xsrc = x + (size_t)(r0 + srow) * D_MODEL + skc;

    const int brow_l = wm * 16 + l15;   // block-local batch row (lane's D col)
    const int brow   = r0 + brow_l;
    const int rb     = wg * 16 + lg * 4;

    f32x4 acc[3];
    #pragma unroll
    for (int g = 0; g < 3; ++g) acc[g] = (f32x4){0.f, 0.f, 0.f, 0.f};

    // prologue: chunk 0 x into regs
    f32x4 vx0 = *(const f32x4*)(xsrc);
    f32x4 vx1 = *(const f32x4*)(xsrc + 4);
    f32x4 vx2 = *(const f32x4*)(xsrc + 8);
    f32x4 vx3 = *(const f32x4*)(xsrc + 12);

    for (int c = 0; c < D_MODEL / CHUNK; ++c) {
        __syncthreads();                 // chunk c-1 readers done; LDS free
        {                                 // convert + write 16 floats -> LDS
            u16x4 h, l;
            #pragma unroll
            for (int j = 0; j < 4; ++j) { h[j]=f2bf(vx0[j]); l[j]=f2bf(vx0[j]-bf2f(h[j])); }
            *(u16x4*)(xa_hi + srow * LDAC + skc)      = h;
            *(u16x4*)(xa_lo + srow * LDAC + skc)      = l;
            #pragma unroll
            for (int j = 0; j < 4; ++j) { h[j]=f2bf(vx1[j]); l[j]=f2bf(vx1[j]-bf2f(h[j])); }
            *(u16x4*)(xa_hi + srow * LDAC + skc + 4)  = h;
            *(u16x4*)(xa_lo + srow * LDAC + skc + 4)  = l;
            #pragma unroll
            for (int j = 0; j < 4; ++j) { h[j]=f2bf(vx2[j]); l[j]=f2bf(vx2[j]-bf2f(h[j])); }
            *(u16x4*)(xa_hi + srow * LDAC + skc + 8)  = h;
            *(u16x4*)(xa_lo + srow * LDAC + skc + 8)  = l;
            #pragma unroll
            for (int j = 0; j < 4; ++j) { h[j]=f2bf(vx3[j]); l[j]=f2bf(vx3[j]-bf2f(h[j])); }
            *(u16x4*)(xa_hi + srow * LDAC + skc + 12) = h;
            *(u16x4*)(xa_lo + srow * LDAC + skc + 12) = l;
        }
        __syncthreads();
        if (c < D_MODEL / CHUNK - 1) {   // next-chunk x: issued here, consumed
            const float* nsrc = xsrc + (c + 1) * CHUNK;   // next barrier-pair
            vx0 = *(const f32x4*)(nsrc);
            vx1 = *(const f32x4*)(nsrc + 4);
            vx2 = *(const f32x4*)(nsrc + 8);
            vx3 = *(const f32x4*)(nsrc + 12);
        }

        // ---- software-pipelined kwin loop: 2-deep weight double-buffer ----
        const int kwbase = c * (CHUNK / 32);
        bf16x8 wbh[2][3], wbl[2][3];     // [buf][g]; all indices static after unroll
        #pragma unroll
        for (int g = 0; g < 3; ++g) {
            const size_t p0 = (((size_t)((g << 2) + wg) * 64 + kwbase    ) * 64 + lane) * 8;
            const size_t p1 = (((size_t)((g << 2) + wg) * 64 + kwbase + 1) * 64 + lane) * 8;
            wbh[0][g] = *(const bf16x8*)(p1_hi + p0);
            wbl[0][g] = *(const bf16x8*)(p1_lo + p0);
            wbh[1][g] = *(const bf16x8*)(p1_hi + p1);
            wbl[1][g] = *(const bf16x8*)(p1_lo + p1);
        }
        #pragma unroll
        for (int kw = 0; kw < CHUNK / 32; ++kw) {
            const int buf = kw & 1;
            const int xoff = brow_l * LDAC + kw * 32 + lg * 8;
            const bf16x8 xh = *(const bf16x8*)(xa_hi + xoff);
            const bf16x8 xl = *(const bf16x8*)(xa_lo + xoff);
            __builtin_amdgcn_s_setprio(1);
            #pragma unroll
            for (int g = 0; g < 3; ++g) {
                acc[g] = MFMA(wbh[buf][g], xh, acc[g]);   // hi*hi
                acc[g] = MFMA(wbl[buf][g], xh, acc[g]);   // lo*hi
                acc[g] = MFMA(wbh[buf][g], xl, acc[g]);   // hi*lo
            }
            __builtin_amdgcn_s_setprio(0);
            if (kw < CHUNK / 32 - 2) {   // refill this buffer for kwin kw+2
                #pragma unroll
                for (int g = 0; g < 3; ++g) {
                    const size_t pn = (((size_t)((g << 2) + wg) * 64 + kwbase + kw + 2) * 64 + lane) * 8;
                    wbh[buf][g] = *(const bf16x8*)(p1_hi + pn);
                    wbl[buf][g] = *(const bf16x8*)(p1_lo + pn);
                }
            }
        }
    }

    // ---------------- middle: vectorized state update ----------------
    float* out_main = dout;
    float* out_nre  = dout + (size_t)BATCH * D_MODEL;
    float* out_nim  = out_nre + (size_t)BATCH * RANK;

    const f32x4 sre4 = *(const f32x4*)(state_re + (size_t)brow * RANK + rb);
    const f32x4 sim4 = *(const f32x4*)(state_im + (size_t)brow * RANK + rb);
    const f32x4 bdt4 = *(const f32x4*)(b_dt   + rb);
    const f32x4 bph4 = *(const f32x4*)(b_ph   + rb);
    const f32x4 Are4 = *(const f32x4*)(A_real + rb);
    const f32x4 Aim4 = *(const f32x4*)(A_imag + rb);

    f32x4 nre4, nim4;
    u16x4 nh4, nl4;
    #pragma unroll
    for (int j = 0; j < 4; ++j) {
        const float ydt = acc[0][j] + bdt4[j];
        const float dtv = fmaxf(ydt, 0.f) + log1pf(expf(-fabsf(ydt)));  // softplus
        const float ph  = tanhf(acc[1][j] + bph4[j]) * 3.14159274101257324f;
        const float decay = expf(-dtv * expf(Are4[j]));
        const float angle = fmaf(dtv, Aim4[j], ph);
        float sn, cs;
        sincosf(angle, &sn, &cs);
        nre4[j] = (sre4[j] * cs - sim4[j] * sn) * decay + acc[2][j];
        nim4[j] = (sre4[j] * sn + sim4[j] * cs) * decay;
        const u16 h = f2bf(nre4[j]);
        nh4[j] = h;
        nl4[j] = f2bf(nre4[j] - bf2f(h));
    }
    *(f32x4*)(out_nre + (size_t)brow * RANK + rb) = nre4;
    *(f32x4*)(out_nim + (size_t)brow * RANK + rb) = nim4;
    *(u16x4*)(nr_hi + brow_l * LDAN + rb) = nh4;
    *(u16x4*)(nr_lo + brow_l * LDAN + rb) = nl4;
    __syncthreads();

    // ---------------- stage 2: out = new_re @ W_C^T (1-deep prefetch) ----------------
    bf16x8 nh[2], nl[2];
    #pragma unroll
    for (int kk = 0; kk < 2; ++kk) {
        const int off = brow_l * LDAN + kk * 32 + lg * 8;
        nh[kk] = *(const bf16x8*)(nr_hi + off);
        nl[kk] = *(const bf16x8*)(nr_lo + off);
    }

    bf16x8 ch[2], cl[2], chn[2], cln[2];
    {
        const int dtile0 = wg << 5;
        #pragma unroll
        for (int kk = 0; kk < 2; ++kk) {
            const size_t poff = (((size_t)dtile0 * 2 + kk) * 64 + lane) * 8;
            ch[kk] = *(const bf16x8*)(p2_hi + poff);
            cl[kk] = *(const bf16x8*)(p2_lo + poff);
        }
    }
    for (int nt = 0; nt < 32; ++nt) {
        if (nt < 31) {
            const int dtn = (wg << 5) + nt + 1;
            #pragma unroll
            for (int kk = 0; kk < 2; ++kk) {
                const size_t poff = (((size_t)dtn * 2 + kk) * 64 + lane) * 8;
                chn[kk] = *(const bf16x8*)(p2_hi + poff);
                cln[kk] = *(const bf16x8*)(p2_lo + poff);
            }
        }
        f32x4 o = (f32x4){0.f, 0.f, 0.f, 0.f};
        __builtin_amdgcn_s_setprio(1);
        #pragma unroll
        for (int kk = 0; kk < 2; ++kk) {
            o = MFMA(ch[kk], nh[kk], o);
            o = MFMA(cl[kk], nh[kk], o);
            o = MFMA(ch[kk], nl[kk], o);
        }
        __builtin_amdgcn_s_setprio(0);
        const int dtile = (wg << 5) + nt;
        *(f32x4*)(out_main + (size_t)brow * D_MODEL + dtile * 16 + lg * 4) = o;
        #pragma unroll
        for (int kk = 0; kk < 2; ++kk) { ch[kk] = chn[kk]; cl[kk] = cln[kk]; }
    }
}

extern "C" void kernel_launch(void* const* d_in, const int* in_sizes, int n_in,
                              void* d_out, int out_size, void* d_ws, size_t ws_size,
                              hipStream_t stream)
{
    const float* x        = (const float*)d_in[0];
    const float* state_re = (const float*)d_in[1];
    const float* state_im = (const float*)d_in[2];
    const float* W_dt     = (const float*)d_in[3];
    const float* b_dt     = (const float*)d_in[4];
    const float* W_ph     = (const float*)d_in[5];
    const float* b_ph     = (const float*)d_in[6];
    const float* W_B      = (const float*)d_in[7];
    const float* W_C      = (const float*)d_in[8];
    const float* A_real   = (const float*)d_in[9];
    const float* A_imag   = (const float*)d_in[10];
    u16*   ws  = (u16*)d_ws;     // needs 2 MiB
    float* out = (float*)d_out;

    prep_pack<<<256, 256, 0, stream>>>(W_dt, W_ph, W_B, W_C, ws);
    mamba_v4<<<BATCH / BM, 512, 0, stream>>>(x, state_re, state_im, b_dt, b_ph,
                                             A_real, A_imag, ws, out);
}